// Round 1
// 1215.749 us; speedup vs baseline: 2.5003x; 2.5003x over previous
//
#include <hip/hip_runtime.h>
#include <hip/hip_bf16.h>

namespace {
constexpr int B = 16, T = 500, C = 512, KW = 7, NH = 8, HD = 64, HID = 2048;
constexpr int M = B * T;             // 8000 rows
constexpr float SCALE = 0.125f;      // 1/sqrt(HD)
constexpr int BTC = B * T * C;       // 4,096,000
// weight arena segment offsets (bf16 element offsets)
constexpr int CC = C * C;                      // 262144
constexpr int SEG_PW0 = 0;
constexpr int SEG_PW1 = CC;
constexpr int SEG_WQ  = 2 * CC;
constexpr int SEG_WK  = 3 * CC;
constexpr int SEG_WV  = 4 * CC;
constexpr int SEG_WO  = 5 * CC;
constexpr int SEG_W1  = 6 * CC;                // 1572864
constexpr int SEG_W2  = 6 * CC + HID * C;     // 2621440
constexpr int SEG_END = 6 * CC + 2 * HID * C; // 3670016
}

typedef short s16x8 __attribute__((ext_vector_type(8)));   // 8 bf16 (4 VGPRs)
typedef float f32x4v __attribute__((ext_vector_type(4)));  // MFMA acc

__device__ __forceinline__ unsigned int bfrne(float f) {  // f32 -> bf16 RNE
  unsigned int u = __float_as_uint(f);
  return (u + 0x7fffu + ((u >> 16) & 1u)) >> 16;
}
__device__ __forceinline__ unsigned int pack2(float a, float b) {
  return bfrne(a) | (bfrne(b) << 16);
}

// ---------------- f32 -> bf16 bulk convert (8 elems/thread) -----------------
__global__ __launch_bounds__(256) void cvtx_kernel(
    const float* __restrict__ X, unsigned short* __restrict__ Y) {
  size_t e = ((size_t)blockIdx.x * 256 + threadIdx.x) * 8;
  float4 a = *(const float4*)(X + e);
  float4 b = *(const float4*)(X + e + 4);
  uint4 o;
  o.x = pack2(a.x, a.y); o.y = pack2(a.z, a.w);
  o.z = pack2(b.x, b.y); o.w = pack2(b.z, b.w);
  *(uint4*)(Y + e) = o;
}

// -------- per-layer weight convert: 8 tensors -> bf16 arena (1 launch) ------
__global__ __launch_bounds__(256) void cvtw_kernel(
    const float* __restrict__ pw0, const float* __restrict__ pw1,
    const float* __restrict__ wqp, const float* __restrict__ wkp,
    const float* __restrict__ wvp, const float* __restrict__ wop,
    const float* __restrict__ w1p, const float* __restrict__ w2p,
    unsigned short* __restrict__ dst) {
  size_t e = ((size_t)blockIdx.x * 256 + threadIdx.x) * 8;
  const float* src;
  size_t off;
  if      (e < SEG_PW1) { src = pw0; off = e - SEG_PW0; }
  else if (e < SEG_WQ)  { src = pw1; off = e - SEG_PW1; }
  else if (e < SEG_WK)  { src = wqp; off = e - SEG_WQ; }
  else if (e < SEG_WV)  { src = wkp; off = e - SEG_WK; }
  else if (e < SEG_WO)  { src = wvp; off = e - SEG_WV; }
  else if (e < SEG_W1)  { src = wop; off = e - SEG_WO; }
  else if (e < SEG_W2)  { src = w1p; off = e - SEG_W1; }
  else                  { src = w2p; off = e - SEG_W2; }
  float4 a = *(const float4*)(src + off);
  float4 b = *(const float4*)(src + off + 4);
  uint4 o;
  o.x = pack2(a.x, a.y); o.y = pack2(a.z, a.w);
  o.z = pack2(b.x, b.y); o.w = pack2(b.z, b.w);
  *(uint4*)(dst + e) = o;
}

// ---------------- MFMA bf16 GEMM: Y[M,N] = X[M,K] @ W[N,K]^T + bias ---------
// 128x128 tile, BK=32, 4 waves of 64x64, register-prefetch staging.
// A-frag: lane holds X[m=lane&15][k=quad*8+j]; B-frag: W[n=lane&15][k=...].
// C/D: col=lane&15, row=quad*4+reg.
template <bool XBF, bool RELU, bool YBF>
__global__ __launch_bounds__(256) void gemm_mfma(
    const void* __restrict__ Xv, const unsigned short* __restrict__ Wb,
    const float* __restrict__ bias, void* __restrict__ Yv, int N, int K) {
  __shared__ unsigned short As[128 * 40];  // row-pad 40 (2-way banks, free)
  __shared__ unsigned short Bs[128 * 40];
  const int tid = threadIdx.x;
  const int n0 = blockIdx.x * 128, m0 = blockIdx.y * 128;
  const int w = tid >> 6, lane = tid & 63;
  const int mh = (w & 1) * 64, nh = (w >> 1) * 64;
  const int quad = lane >> 4, r15 = lane & 15;

  // staging: 2 groups of 8 consecutive k per thread, for A and B tiles
  const int row0 = tid >> 2,           kq0 = (tid & 3) * 8;
  const int row1 = (tid + 256) >> 2,   kq1 = (tid & 3) * 8;
  const int xr0 = min(m0 + row0, M - 1), xr1 = min(m0 + row1, M - 1);
  const int wr0 = n0 + row0, wr1 = n0 + row1;

  f32x4v acc[4][4];
#pragma unroll
  for (int i = 0; i < 4; ++i)
#pragma unroll
    for (int j = 0; j < 4; ++j) acc[i][j] = {0.f, 0.f, 0.f, 0.f};

  auto loadX = [&](int k0, int xr, int kq) -> uint4 {
    if (XBF) {
      return *(const uint4*)((const unsigned short*)Xv + (size_t)xr * K + k0 + kq);
    } else {
      const float* xp = (const float*)Xv + (size_t)xr * K + k0 + kq;
      float4 a = *(const float4*)xp;
      float4 b = *(const float4*)(xp + 4);
      uint4 o;
      o.x = pack2(a.x, a.y); o.y = pack2(a.z, a.w);
      o.z = pack2(b.x, b.y); o.w = pack2(b.z, b.w);
      return o;
    }
  };
  auto loadW = [&](int k0, int wr, int kq) -> uint4 {
    return *(const uint4*)(Wb + (size_t)wr * K + k0 + kq);
  };

  uint4 xv0 = loadX(0, xr0, kq0), xv1 = loadX(0, xr1, kq1);
  uint4 wv0 = loadW(0, wr0, kq0), wv1 = loadW(0, wr1, kq1);
  const int nk = K / 32;
  for (int c = 0; c < nk; ++c) {
    __syncthreads();
    *(uint4*)&As[row0 * 40 + kq0] = xv0;
    *(uint4*)&As[row1 * 40 + kq1] = xv1;
    *(uint4*)&Bs[row0 * 40 + kq0] = wv0;
    *(uint4*)&Bs[row1 * 40 + kq1] = wv1;
    __syncthreads();
    if (c + 1 < nk) {
      int k0 = (c + 1) * 32;
      xv0 = loadX(k0, xr0, kq0); xv1 = loadX(k0, xr1, kq1);
      wv0 = loadW(k0, wr0, kq0); wv1 = loadW(k0, wr1, kq1);
    }
    s16x8 af[4], bg[4];
#pragma unroll
    for (int im = 0; im < 4; ++im)
      af[im] = *(const s16x8*)&As[(mh + im * 16 + r15) * 40 + quad * 8];
#pragma unroll
    for (int in = 0; in < 4; ++in)
      bg[in] = *(const s16x8*)&Bs[(nh + in * 16 + r15) * 40 + quad * 8];
#pragma unroll
    for (int in = 0; in < 4; ++in)
#pragma unroll
      for (int im = 0; im < 4; ++im)
        acc[im][in] = __builtin_amdgcn_mfma_f32_16x16x32_bf16(
            af[im], bg[in], acc[im][in], 0, 0, 0);
  }
  // epilogue
#pragma unroll
  for (int in = 0; in < 4; ++in) {
    int col = n0 + nh + in * 16 + r15;
    float bv = bias[col];
#pragma unroll
    for (int im = 0; im < 4; ++im) {
      int rowb = m0 + mh + im * 16 + quad * 4;
#pragma unroll
      for (int r = 0; r < 4; ++r) {
        int row = rowb + r;
        if (row < M) {
          float v = acc[im][in][r] + bv;
          if (RELU) v = fmaxf(v, 0.f);
          if (YBF)
            ((unsigned short*)Yv)[(size_t)row * N + col] =
                (unsigned short)bfrne(v);
          else
            ((float*)Yv)[(size_t)row * N + col] = v;
        }
      }
    }
  }
}

// ---------------- depthwise conv (K=7, pad 3) along T, layout (B,T,C) -------
__global__ __launch_bounds__(256) void dwconv_kernel(
    const float* __restrict__ X, const float* __restrict__ W,
    const float* __restrict__ bias, float* __restrict__ Y) {
  int gid = blockIdx.x * 256 + threadIdx.x;  // 0 .. T*C-1
  int b = blockIdx.y;
  int t = gid >> 9;
  int c = gid & 511;
  float acc = bias[c];
  size_t base = (size_t)b * T * C;
#pragma unroll
  for (int k = 0; k < KW; ++k) {
    int tt = t + k - 3;
    if (tt >= 0 && tt < T) acc += X[base + (size_t)tt * C + c] * W[c * KW + k];
  }
  Y[base + gid] = acc;
}

// ---------------- row LayerNorm over C=512, one wave per row ----------------
__global__ __launch_bounds__(256) void ln_kernel(
    const float* __restrict__ X, const float* __restrict__ g,
    const float* __restrict__ bta, float* __restrict__ Y) {
  int row = blockIdx.x * 4 + (threadIdx.x >> 6);
  int lane = threadIdx.x & 63;
  const float* x = X + (size_t)row * C;
  float v[8];
  float s = 0.f, ss = 0.f;
#pragma unroll
  for (int i = 0; i < 8; ++i) {
    v[i] = x[lane + i * 64];
    s += v[i];
    ss += v[i] * v[i];
  }
#pragma unroll
  for (int off = 32; off; off >>= 1) {
    s += __shfl_xor(s, off);
    ss += __shfl_xor(ss, off);
  }
  float mean = s * (1.f / C);
  float var = ss * (1.f / C) - mean * mean;
  var = fmaxf(var, 0.f);
  float rstd = rsqrtf(var + 1e-5f);
  float* y = Y + (size_t)row * C;
#pragma unroll
  for (int i = 0; i < 8; ++i) {
    int c = lane + i * 64;
    y[c] = (v[i] - mean) * rstd * g[c] + bta[c];
  }
}

// ---------- causal flash attention, MFMA bf16 -------------------------------
// Block = (64-query tile, head, batch); 4 waves, wave w owns q rows
// [q0+16w, q0+16w+16). Key tiles of 64. S = (Q*SCALE) @ K^T via
// mfma_f32_16x16x32_bf16 (K staged [key][d] in LDS); online softmax in f32
// with 16-lane shfl_xor row reductions; P -> bf16 via per-wave LDS round-trip
// feeds PV MFMA against V staged TRANSPOSED ([d][key]) in LDS.
// LDK=72 (pad 8 bf16) breaks the stride-128B bank alignment.
__global__ __launch_bounds__(256) void attn_mfma_kernel(
    const float* __restrict__ Qg, const float* __restrict__ Kg,
    const float* __restrict__ Vg, float* __restrict__ Yg) {
  constexpr int LDK = 72;
  __shared__ __align__(16) unsigned short Ks[64 * LDK];     // [key][d]
  __shared__ __align__(16) unsigned short Vt[64 * LDK];     // [d][key]
  __shared__ __align__(16) unsigned short Ps[4][16 * LDK];  // per-wave [q][key]
  const int tid = threadIdx.x;
  const int lane = tid & 63, w = tid >> 6;
  const int quad = lane >> 4, r15 = lane & 15;
  const int qt = blockIdx.x, hh = blockIdx.y, b = blockIdx.z;
  const int q0 = qt * 64;
  const size_t cbase = (size_t)hh * HD;
  const size_t bTC = (size_t)b * T * C;

  // Q A-frags (scale folded): lane holds Q[q0+16w+r15][ks*32+quad*8 .. +8)
  s16x8 qa[2];
  {
    int qr = min(q0 + w * 16 + r15, T - 1);
    const float* qp = Qg + bTC + (size_t)qr * C + cbase;
#pragma unroll
    for (int ks = 0; ks < 2; ++ks) {
      float4 a = *(const float4*)(qp + ks * 32 + quad * 8);
      float4 c = *(const float4*)(qp + ks * 32 + quad * 8 + 4);
      uint4 o;
      o.x = pack2(a.x * SCALE, a.y * SCALE);
      o.y = pack2(a.z * SCALE, a.w * SCALE);
      o.z = pack2(c.x * SCALE, c.y * SCALE);
      o.w = pack2(c.z * SCALE, c.w * SCALE);
      qa[ks] = *(s16x8*)&o;
    }
  }

  f32x4v oacc[4];
  float mm[4], ll[4];
#pragma unroll
  for (int i = 0; i < 4; ++i) {
    oacc[i] = {0.f, 0.f, 0.f, 0.f};
    mm[i] = -1e30f;
    ll[i] = 0.f;
  }

  // staging maps: K rows (coalesced 64B chunks), V as 4x4 transpose sub-tiles
  const int krow = tid >> 2, kd = (tid & 3) * 4;
  const int vk4 = (tid >> 4) * 4, vd4 = (tid & 15) * 4;

  const int kend = min(q0 + 63, T - 1);
  for (int key0 = 0; key0 <= kend; key0 += 64) {
    __syncthreads();
    // ---- stage K tile [key][d] ----
    {
      int key = key0 + krow;
      if (key < T) {
        const float* kp = Kg + bTC + (size_t)key * C + cbase + kd;
#pragma unroll
        for (int u = 0; u < 4; ++u) {
          float4 kk = *(const float4*)(kp + u * 16);
          uint2 o2;
          o2.x = pack2(kk.x, kk.y);
          o2.y = pack2(kk.z, kk.w);
          *(uint2*)&Ks[krow * LDK + kd + u * 16] = o2;
        }
      } else {
        uint2 z;
        z.x = 0u; z.y = 0u;
#pragma unroll
        for (int u = 0; u < 4; ++u)
          *(uint2*)&Ks[krow * LDK + kd + u * 16] = z;
      }
    }
    // ---- stage V tile transposed [d][key] ----
    {
      __align__(16) float va[4][4];
#pragma unroll
      for (int j = 0; j < 4; ++j) {
        int key = key0 + vk4 + j;
        if (key < T) {
          *(float4*)va[j] =
              *(const float4*)(Vg + bTC + (size_t)key * C + cbase + vd4);
        } else {
          va[j][0] = 0.f; va[j][1] = 0.f; va[j][2] = 0.f; va[j][3] = 0.f;
        }
      }
#pragma unroll
      for (int i = 0; i < 4; ++i) {
        uint2 o2;
        o2.x = pack2(va[0][i], va[1][i]);
        o2.y = pack2(va[2][i], va[3][i]);
        *(uint2*)&Vt[(vd4 + i) * LDK + vk4] = o2;
      }
    }
    __syncthreads();

    // ---- S = Q K^T (per wave: 16 q x 64 keys) ----
    f32x4v sa[4];
#pragma unroll
    for (int nt = 0; nt < 4; ++nt) {
      s16x8 kb0 = *(const s16x8*)&Ks[(nt * 16 + r15) * LDK + quad * 8];
      s16x8 kb1 = *(const s16x8*)&Ks[(nt * 16 + r15) * LDK + 32 + quad * 8];
      f32x4v z = {0.f, 0.f, 0.f, 0.f};
      z = __builtin_amdgcn_mfma_f32_16x16x32_bf16(qa[0], kb0, z, 0, 0, 0);
      z = __builtin_amdgcn_mfma_f32_16x16x32_bf16(qa[1], kb1, z, 0, 0, 0);
      sa[nt] = z;
    }
    const bool diag = (key0 == q0);  // only the diagonal tile needs masking

    // ---- online softmax (f32); C-layout row = quad*4+r, col = nt*16+r15 ----
#pragma unroll
    for (int r = 0; r < 4; ++r) {
      int q = q0 + w * 16 + quad * 4 + r;
      float sv[4];
#pragma unroll
      for (int nt = 0; nt < 4; ++nt) {
        sv[nt] = sa[nt][r];
        if (diag && (key0 + nt * 16 + r15 > q)) sv[nt] = -1e30f;
      }
      float mx = fmaxf(fmaxf(sv[0], sv[1]), fmaxf(sv[2], sv[3]));
      mx = fmaxf(mx, __shfl_xor(mx, 8));
      mx = fmaxf(mx, __shfl_xor(mx, 4));
      mx = fmaxf(mx, __shfl_xor(mx, 2));
      mx = fmaxf(mx, __shfl_xor(mx, 1));
      float mnew = fmaxf(mm[r], mx);
      float alpha = __expf(mm[r] - mnew);
      float ps = 0.f;
#pragma unroll
      for (int nt = 0; nt < 4; ++nt) {
        float p = __expf(sv[nt] - mnew);
        ps += p;
        Ps[w][(quad * 4 + r) * LDK + nt * 16 + r15] =
            (unsigned short)bfrne(p);
      }
      ps += __shfl_xor(ps, 8);
      ps += __shfl_xor(ps, 4);
      ps += __shfl_xor(ps, 2);
      ps += __shfl_xor(ps, 1);
      ll[r] = ll[r] * alpha + ps;
      mm[r] = mnew;
#pragma unroll
      for (int dt = 0; dt < 4; ++dt) oacc[dt][r] *= alpha;
    }
    // per-wave LDS round-trip: drain this wave's Ps writes before reading
    asm volatile("s_waitcnt lgkmcnt(0)" ::: "memory");
    __builtin_amdgcn_sched_barrier(0);

    // ---- O += P @ V ----
    s16x8 pa0 = *(const s16x8*)&Ps[w][r15 * LDK + quad * 8];
    s16x8 pa1 = *(const s16x8*)&Ps[w][r15 * LDK + 32 + quad * 8];
#pragma unroll
    for (int dt = 0; dt < 4; ++dt) {
      s16x8 vb0 = *(const s16x8*)&Vt[(dt * 16 + r15) * LDK + quad * 8];
      s16x8 vb1 = *(const s16x8*)&Vt[(dt * 16 + r15) * LDK + 32 + quad * 8];
      oacc[dt] =
          __builtin_amdgcn_mfma_f32_16x16x32_bf16(pa0, vb0, oacc[dt], 0, 0, 0);
      oacc[dt] =
          __builtin_amdgcn_mfma_f32_16x16x32_bf16(pa1, vb1, oacc[dt], 0, 0, 0);
    }
  }

  // ---- write out (C-layout: row = quad*4+r, col = dt*16+r15) ----
#pragma unroll
  for (int r = 0; r < 4; ++r) {
    int q = q0 + w * 16 + quad * 4 + r;
    if (q < T) {
      float inv = 1.f / ll[r];
      float* yp = Yg + bTC + (size_t)q * C + cbase;
#pragma unroll
      for (int dt = 0; dt < 4; ++dt) yp[dt * 16 + r15] = oacc[dt][r] * inv;
    }
  }
}

extern "C" void kernel_launch(void* const* d_in, const int* in_sizes, int n_in,
                              void* d_out, int out_size, void* d_ws,
                              size_t ws_size, hipStream_t stream) {
  const float* x     = (const float*)d_in[0];
  const float* dw_w  = (const float*)d_in[1];
  const float* dw_b  = (const float*)d_in[2];
  const float* pw_w  = (const float*)d_in[3];
  const float* pw_b  = (const float*)d_in[4];
  const float* cln_g = (const float*)d_in[5];
  const float* cln_b = (const float*)d_in[6];
  const float* wq    = (const float*)d_in[7];
  const float* bq    = (const float*)d_in[8];
  const float* wk    = (const float*)d_in[9];
  const float* bk    = (const float*)d_in[10];
  const float* wv    = (const float*)d_in[11];
  const float* bv    = (const float*)d_in[12];
  const float* wo    = (const float*)d_in[13];
  const float* bo    = (const float*)d_in[14];
  const float* aln_g = (const float*)d_in[15];
  const float* aln_b = (const float*)d_in[16];
  const float* w1    = (const float*)d_in[17];
  const float* b1    = (const float*)d_in[18];
  const float* w2    = (const float*)d_in[19];
  const float* b2    = (const float*)d_in[20];
  const float* fln_g = (const float*)d_in[21];
  const float* fln_b = (const float*)d_in[22];

  float* ws = (float*)d_ws;
  float* A  = ws;                      // [0,BTC)  f32 scratch
  float* Bf = ws + (size_t)BTC;        // [BTC,2BTC)  xbf slot (as ushort)
  float* R0 = ws + (size_t)2 * BTC;    // Q / GEMM outs
  float* R1 = ws + (size_t)3 * BTC;    // K / ffn1 xbf
  float* R2 = ws + (size_t)4 * BTC;    // V
  unsigned short* WA = (unsigned short*)(ws + (size_t)5 * BTC);  // 7.4 MB
  float* out = (float*)d_out;          // 3 layer outputs, f32

  unsigned short* xbf  = (unsigned short*)Bf;
  unsigned short* fbf  = (unsigned short*)R1;   // ffn1 input bf16
  unsigned short* hbf  = (unsigned short*)A;    // ffn1 output bf16 (spans A,Bf)

  dim3 blk(256);
  dim3 gemmC(C / 128, 63);      // N=512
  dim3 gemmH(HID / 128, 63);    // N=2048
  dim3 convG(T * C / 256, B);
  dim3 attnG((T + 63) / 64, NH, B);
  int cvtxB = BTC / 2048;       // 2000 blocks
  int cvtwB = SEG_END / 2048;   // 1792 blocks

  for (int l = 0; l < 3; ++l) {
    float* h = out + (size_t)l * BTC;
    const float* hin = (l == 0) ? x : out + (size_t)(l - 1) * BTC;
    cvtw_kernel<<<cvtwB, blk, 0, stream>>>(
        pw_w + (size_t)(2 * l) * CC, pw_w + (size_t)(2 * l + 1) * CC,
        wq + (size_t)l * CC, wk + (size_t)l * CC, wv + (size_t)l * CC,
        wo + (size_t)l * CC, w1 + (size_t)l * HID * C,
        w2 + (size_t)l * C * HID, WA);
    // ---- 2 conv blocks ----
    for (int cb = 0; cb < 2; ++cb) {
      int lc = l * 2 + cb;
      const float* src = (cb == 0) ? hin : h;
      dwconv_kernel<<<convG, blk, 0, stream>>>(src, dw_w + (size_t)lc * C * KW,
                                               dw_b + (size_t)lc * C, A);
      cvtx_kernel<<<cvtxB, blk, 0, stream>>>(A, xbf);
      gemm_mfma<true, false, false><<<gemmC, blk, 0, stream>>>(
          xbf, WA + (cb ? SEG_PW1 : SEG_PW0), pw_b + (size_t)lc * C, R0, C, C);
      ln_kernel<<<M / 4, blk, 0, stream>>>(R0, cln_g + (size_t)lc * C,
                                           cln_b + (size_t)lc * C, h);
    }
    // ---- attention ----
    cvtx_kernel<<<cvtxB, blk, 0, stream>>>(h, xbf);
    gemm_mfma<true, false, false><<<gemmC, blk, 0, stream>>>(
        xbf, WA + SEG_WQ, bq + (size_t)l * C, R0, C, C);
    gemm_mfma<true, false, false><<<gemmC, blk, 0, stream>>>(
        xbf, WA + SEG_WK, bk + (size_t)l * C, R1, C, C);
    gemm_mfma<true, false, false><<<gemmC, blk, 0, stream>>>(
        xbf, WA + SEG_WV, bv + (size_t)l * C, R2, C, C);
    attn_mfma_kernel<<<attnG, blk, 0, stream>>>(R0, R1, R2, A);
    cvtx_kernel<<<cvtxB, blk, 0, stream>>>(A, xbf);
    gemm_mfma<true, false, false><<<gemmC, blk, 0, stream>>>(
        xbf, WA + SEG_WO, bo + (size_t)l * C, R0, C, C);
    ln_kernel<<<M / 4, blk, 0, stream>>>(R0, aln_g + (size_t)l * C,
                                         aln_b + (size_t)l * C, h);
    // ---- FFN ----
    cvtx_kernel<<<cvtxB, blk, 0, stream>>>(h, fbf);
    gemm_mfma<true, true, true><<<gemmH, blk, 0, stream>>>(
        fbf, WA + SEG_W1, b1 + (size_t)l * HID, hbf, HID, C);
    gemm_mfma<true, false, false><<<gemmC, blk, 0, stream>>>(
        hbf, WA + SEG_W2, b2 + (size_t)l * C, R0, C, HID);
    ln_kernel<<<M / 4, blk, 0, stream>>>(R0, fln_g + (size_t)l * C,
                                         fln_b + (size_t)l * C, h);
  }
}

// Round 2
// 1066.755 us; speedup vs baseline: 2.8495x; 1.1397x over previous
//
#include <hip/hip_runtime.h>
#include <hip/hip_bf16.h>

namespace {
constexpr int B = 16, T = 500, C = 512, KW = 7, NH = 8, HD = 64, HID = 2048;
constexpr int M = B * T;             // 8000 rows
constexpr float SCALE = 0.125f;      // 1/sqrt(HD)
constexpr int BTC = B * T * C;       // 4,096,000
// weight arena segment offsets (bf16 element offsets)
constexpr int CC = C * C;                      // 262144
constexpr int SEG_PW0 = 0;
constexpr int SEG_PW1 = CC;
constexpr int SEG_WQ  = 2 * CC;
constexpr int SEG_WK  = 3 * CC;  // contiguous after WQ -> fused QKV GEMM
constexpr int SEG_WV  = 4 * CC;
constexpr int SEG_WO  = 5 * CC;
constexpr int SEG_W1  = 6 * CC;                // 1572864
constexpr int SEG_W2  = 6 * CC + HID * C;     // 2621440
constexpr int SEG_END = 6 * CC + 2 * HID * C; // 3670016
}

typedef short s16x8 __attribute__((ext_vector_type(8)));   // 8 bf16 (4 VGPRs)
typedef float f32x4v __attribute__((ext_vector_type(4)));  // MFMA acc
typedef unsigned short u16x4 __attribute__((ext_vector_type(4)));

__device__ __forceinline__ unsigned int bfrne(float f) {  // f32 -> bf16 RNE
  unsigned int u = __float_as_uint(f);
  return (u + 0x7fffu + ((u >> 16) & 1u)) >> 16;
}
__device__ __forceinline__ unsigned int pack2(float a, float b) {
  return bfrne(a) | (bfrne(b) << 16);
}

// -------- per-layer weight convert: 8 tensors -> bf16 arena (1 launch) ------
__global__ __launch_bounds__(256) void cvtw_kernel(
    const float* __restrict__ pw0, const float* __restrict__ pw1,
    const float* __restrict__ wqp, const float* __restrict__ wkp,
    const float* __restrict__ wvp, const float* __restrict__ wop,
    const float* __restrict__ w1p, const float* __restrict__ w2p,
    unsigned short* __restrict__ dst) {
  size_t e = ((size_t)blockIdx.x * 256 + threadIdx.x) * 8;
  const float* src;
  size_t off;
  if      (e < SEG_PW1) { src = pw0; off = e - SEG_PW0; }
  else if (e < SEG_WQ)  { src = pw1; off = e - SEG_PW1; }
  else if (e < SEG_WK)  { src = wqp; off = e - SEG_WQ; }
  else if (e < SEG_WV)  { src = wkp; off = e - SEG_WK; }
  else if (e < SEG_WO)  { src = wvp; off = e - SEG_WV; }
  else if (e < SEG_W1)  { src = wop; off = e - SEG_WO; }
  else if (e < SEG_W2)  { src = w1p; off = e - SEG_W1; }
  else                  { src = w2p; off = e - SEG_W2; }
  float4 a = *(const float4*)(src + off);
  float4 b = *(const float4*)(src + off + 4);
  uint4 o;
  o.x = pack2(a.x, a.y); o.y = pack2(a.z, a.w);
  o.z = pack2(b.x, b.y); o.w = pack2(b.z, b.w);
  *(uint4*)(dst + e) = o;
}

// -------- concat bq|bk|bv (512 each) into one 1536 bias vector --------------
__global__ __launch_bounds__(256) void biascat_kernel(
    const float* __restrict__ bq, const float* __restrict__ bk,
    const float* __restrict__ bv, float* __restrict__ dst) {
  int i = blockIdx.x * 256 + threadIdx.x;  // 0..1535
  float v = (i < 512) ? bq[i] : (i < 1024 ? bk[i - 512] : bv[i - 1024]);
  dst[i] = v;
}

// ---------------- MFMA bf16 GEMM: Y[M,N] = X[M,K] @ W[N,K]^T + bias ---------
// 128x128 tile, BK=32, 4 waves of 64x64, double-buffered LDS (1 barrier/step),
// register-prefetch staging.
// A-frag: lane holds X[m=lane&15][k=quad*8+j]; B-frag: W[n=lane&15][k=...].
// C/D: col=lane&15, row=quad*4+reg.
template <bool XBF, bool RELU, bool YBF>
__global__ __launch_bounds__(256) void gemm_mfma(
    const void* __restrict__ Xv, const unsigned short* __restrict__ Wb,
    const float* __restrict__ bias, void* __restrict__ Yv, int N, int K) {
  __shared__ unsigned short As[2][128 * 40];  // row-pad 40 (2-way banks, free)
  __shared__ unsigned short Bs[2][128 * 40];
  const int tid = threadIdx.x;
  const int n0 = blockIdx.x * 128, m0 = blockIdx.y * 128;
  const int w = tid >> 6, lane = tid & 63;
  const int mh = (w & 1) * 64, nh = (w >> 1) * 64;
  const int quad = lane >> 4, r15 = lane & 15;

  // staging: 2 groups of 8 consecutive k per thread, for A and B tiles
  const int row0 = tid >> 2,           kq0 = (tid & 3) * 8;
  const int row1 = (tid + 256) >> 2,   kq1 = (tid & 3) * 8;
  const int xr0 = min(m0 + row0, M - 1), xr1 = min(m0 + row1, M - 1);
  const int wr0 = n0 + row0, wr1 = n0 + row1;

  f32x4v acc[4][4];
#pragma unroll
  for (int i = 0; i < 4; ++i)
#pragma unroll
    for (int j = 0; j < 4; ++j) acc[i][j] = {0.f, 0.f, 0.f, 0.f};

  auto loadX = [&](int k0, int xr, int kq) -> uint4 {
    if (XBF) {
      return *(const uint4*)((const unsigned short*)Xv + (size_t)xr * K + k0 + kq);
    } else {
      const float* xp = (const float*)Xv + (size_t)xr * K + k0 + kq;
      float4 a = *(const float4*)xp;
      float4 b = *(const float4*)(xp + 4);
      uint4 o;
      o.x = pack2(a.x, a.y); o.y = pack2(a.z, a.w);
      o.z = pack2(b.x, b.y); o.w = pack2(b.z, b.w);
      return o;
    }
  };
  auto loadW = [&](int k0, int wr, int kq) -> uint4 {
    return *(const uint4*)(Wb + (size_t)wr * K + k0 + kq);
  };

  uint4 xv0 = loadX(0, xr0, kq0), xv1 = loadX(0, xr1, kq1);
  uint4 wv0 = loadW(0, wr0, kq0), wv1 = loadW(0, wr1, kq1);
  *(uint4*)&As[0][row0 * 40 + kq0] = xv0;
  *(uint4*)&As[0][row1 * 40 + kq1] = xv1;
  *(uint4*)&Bs[0][row0 * 40 + kq0] = wv0;
  *(uint4*)&Bs[0][row1 * 40 + kq1] = wv1;
  int cur = 0;
  const int nk = K / 32;
  for (int c = 0; c < nk; ++c) {
    __syncthreads();
    if (c + 1 < nk) {
      int k0 = (c + 1) * 32;
      xv0 = loadX(k0, xr0, kq0); xv1 = loadX(k0, xr1, kq1);
      wv0 = loadW(k0, wr0, kq0); wv1 = loadW(k0, wr1, kq1);
    }
    const unsigned short* Ac = As[cur];
    const unsigned short* Bc = Bs[cur];
    s16x8 af[4], bg[4];
#pragma unroll
    for (int im = 0; im < 4; ++im)
      af[im] = *(const s16x8*)&Ac[(mh + im * 16 + r15) * 40 + quad * 8];
#pragma unroll
    for (int in = 0; in < 4; ++in)
      bg[in] = *(const s16x8*)&Bc[(nh + in * 16 + r15) * 40 + quad * 8];
#pragma unroll
    for (int in = 0; in < 4; ++in)
#pragma unroll
      for (int im = 0; im < 4; ++im)
        acc[im][in] = __builtin_amdgcn_mfma_f32_16x16x32_bf16(
            af[im], bg[in], acc[im][in], 0, 0, 0);
    if (c + 1 < nk) {
      int nx = cur ^ 1;
      *(uint4*)&As[nx][row0 * 40 + kq0] = xv0;
      *(uint4*)&As[nx][row1 * 40 + kq1] = xv1;
      *(uint4*)&Bs[nx][row0 * 40 + kq0] = wv0;
      *(uint4*)&Bs[nx][row1 * 40 + kq1] = wv1;
      cur = nx;
    }
  }
  // epilogue
#pragma unroll
  for (int in = 0; in < 4; ++in) {
    int col = n0 + nh + in * 16 + r15;
    float bv = bias[col];
#pragma unroll
    for (int im = 0; im < 4; ++im) {
      int rowb = m0 + mh + im * 16 + quad * 4;
#pragma unroll
      for (int r = 0; r < 4; ++r) {
        int row = rowb + r;
        if (row < M) {
          float v = acc[im][in][r] + bv;
          if (RELU) v = fmaxf(v, 0.f);
          if (YBF)
            ((unsigned short*)Yv)[(size_t)row * N + col] =
                (unsigned short)bfrne(v);
          else
            ((float*)Yv)[(size_t)row * N + col] = v;
        }
      }
    }
  }
}

// ------- depthwise conv (K=7, pad 3) along T, (B,T,C), bf16 out, 2 ch/thread
__global__ __launch_bounds__(256) void dwconv_kernel(
    const float* __restrict__ X, const float* __restrict__ W,
    const float* __restrict__ bias, unsigned short* __restrict__ Y) {
  int gid = blockIdx.x * 256 + threadIdx.x;  // 0 .. T*C/2-1
  int b = blockIdx.y;
  int e = gid * 2;
  int t = e >> 9;
  int c = e & 511;  // even
  float acc0 = bias[c], acc1 = bias[c + 1];
  size_t base = (size_t)b * T * C;
#pragma unroll
  for (int k = 0; k < KW; ++k) {
    int tt = t + k - 3;
    if (tt >= 0 && tt < T) {
      float2 xv = *(const float2*)&X[base + (size_t)tt * C + c];
      acc0 += xv.x * W[c * KW + k];
      acc1 += xv.y * W[(c + 1) * KW + k];
    }
  }
  *(unsigned int*)&Y[base + e] = pack2(acc0, acc1);
}

// --------- row LayerNorm over C=512, one wave/row, vectorized, opt bf16 out -
template <bool DUAL>
__global__ __launch_bounds__(256) void ln_kernel(
    const float* __restrict__ X, const float* __restrict__ g,
    const float* __restrict__ bta, float* __restrict__ Y,
    unsigned short* __restrict__ Yb) {
  int row = blockIdx.x * 4 + (threadIdx.x >> 6);
  int lane = threadIdx.x & 63;
  const float* x = X + (size_t)row * C + lane * 8;
  float4 a = *(const float4*)x;
  float4 b2 = *(const float4*)(x + 4);
  float v[8] = {a.x, a.y, a.z, a.w, b2.x, b2.y, b2.z, b2.w};
  float s = 0.f, ss = 0.f;
#pragma unroll
  for (int i = 0; i < 8; ++i) {
    s += v[i];
    ss += v[i] * v[i];
  }
#pragma unroll
  for (int off = 32; off; off >>= 1) {
    s += __shfl_xor(s, off);
    ss += __shfl_xor(ss, off);
  }
  float mean = s * (1.f / C);
  float var = ss * (1.f / C) - mean * mean;
  var = fmaxf(var, 0.f);
  float rstd = rsqrtf(var + 1e-5f);
  float4 g0 = *(const float4*)(g + lane * 8);
  float4 g1 = *(const float4*)(g + lane * 8 + 4);
  float4 be0 = *(const float4*)(bta + lane * 8);
  float4 be1 = *(const float4*)(bta + lane * 8 + 4);
  float gg[8] = {g0.x, g0.y, g0.z, g0.w, g1.x, g1.y, g1.z, g1.w};
  float bb[8] = {be0.x, be0.y, be0.z, be0.w, be1.x, be1.y, be1.z, be1.w};
  float o[8];
#pragma unroll
  for (int i = 0; i < 8; ++i) o[i] = (v[i] - mean) * rstd * gg[i] + bb[i];
  float* y = Y + (size_t)row * C + lane * 8;
  float4 w0 = {o[0], o[1], o[2], o[3]};
  float4 w1 = {o[4], o[5], o[6], o[7]};
  *(float4*)y = w0;
  *(float4*)(y + 4) = w1;
  if (DUAL) {
    uint4 ob;
    ob.x = pack2(o[0], o[1]); ob.y = pack2(o[2], o[3]);
    ob.z = pack2(o[4], o[5]); ob.w = pack2(o[6], o[7]);
    *(uint4*)(Yb + (size_t)row * C + lane * 8) = ob;
  }
}

// ---------- causal flash attention, MFMA bf16, bf16 in (QKV fused) / out ----
// QKV: [M, 1536] bf16 (Q|K|V each 512 cols). Block = (64-q tile, head, batch);
// 4 waves, wave w owns q rows [q0+16w, q0+16w+16). Key tiles of 64.
// S = Q @ K^T via mfma_16x16x32_bf16 (K staged [key][d] in LDS, SCALE applied
// post-MFMA); online softmax in f32 (16-lane shfl reductions); P -> bf16 via
// per-wave LDS round-trip; PV MFMA against V staged transposed [d][key].
__global__ __launch_bounds__(256) void attn_mfma_kernel(
    const unsigned short* __restrict__ QKV, unsigned short* __restrict__ Yb) {
  constexpr int QS = 3 * C;  // 1536
  constexpr int LDK = 72;    // pad breaks 128B-stride bank alignment
  __shared__ __align__(16) unsigned short Ks[64 * LDK];     // [key][d]
  __shared__ __align__(16) unsigned short Vt[64 * LDK];     // [d][key]
  __shared__ __align__(16) unsigned short Ps[4][16 * LDK];  // per-wave [q][key]
  const int tid = threadIdx.x;
  const int lane = tid & 63, w = tid >> 6;
  const int quad = lane >> 4, r15 = lane & 15;
  const int qt = blockIdx.x, hh = blockIdx.y, b = blockIdx.z;
  const int q0 = qt * 64;
  const size_t hbase = (size_t)hh * HD;

  // Q A-frags: lane holds Q[q0+16w+r15][ks*32+quad*8 .. +8)
  s16x8 qa[2];
  {
    int qr = min(q0 + w * 16 + r15, T - 1);
    const unsigned short* qp = QKV + ((size_t)b * T + qr) * QS + hbase;
#pragma unroll
    for (int ks = 0; ks < 2; ++ks)
      qa[ks] = *(const s16x8*)(qp + ks * 32 + quad * 8);
  }

  f32x4v oacc[4];
  float mm[4], ll[4];
#pragma unroll
  for (int i = 0; i < 4; ++i) {
    oacc[i] = {0.f, 0.f, 0.f, 0.f};
    mm[i] = -1e30f;
    ll[i] = 0.f;
  }

  // staging maps
  const int krow = tid >> 2, kd = (tid & 3) * 16;        // K: 16 shorts/thread
  const int vk4 = (tid >> 4) * 4, vd4 = (tid & 15) * 4;  // V: 4x4 transpose

  const int kend = min(q0 + 63, T - 1);
  for (int key0 = 0; key0 <= kend; key0 += 64) {
    __syncthreads();
    // ---- stage K tile [key][d] (bf16 copy) ----
    {
      int key = key0 + krow;
      if (key < T) {
        const unsigned short* kp =
            QKV + ((size_t)b * T + key) * QS + C + hbase + kd;
        uint4 k0 = *(const uint4*)kp;
        uint4 k1 = *(const uint4*)(kp + 8);
        *(uint4*)&Ks[krow * LDK + kd] = k0;
        *(uint4*)&Ks[krow * LDK + kd + 8] = k1;
      } else {
        uint4 z = {0u, 0u, 0u, 0u};
        *(uint4*)&Ks[krow * LDK + kd] = z;
        *(uint4*)&Ks[krow * LDK + kd + 8] = z;
      }
    }
    // ---- stage V tile transposed [d][key] ----
    {
      u16x4 va[4];
#pragma unroll
      for (int j = 0; j < 4; ++j) {
        int key = key0 + vk4 + j;
        if (key < T) {
          va[j] = *(const u16x4*)(QKV + ((size_t)b * T + key) * QS + 2 * C +
                                  hbase + vd4);
        } else {
          va[j] = (u16x4){0, 0, 0, 0};
        }
      }
#pragma unroll
      for (int i = 0; i < 4; ++i) {
        uint2 o2;
        o2.x = (unsigned int)va[0][i] | ((unsigned int)va[1][i] << 16);
        o2.y = (unsigned int)va[2][i] | ((unsigned int)va[3][i] << 16);
        *(uint2*)&Vt[(vd4 + i) * LDK + vk4] = o2;
      }
    }
    __syncthreads();

    // ---- S = Q K^T (per wave: 16 q x 64 keys) ----
    f32x4v sa[4];
#pragma unroll
    for (int nt = 0; nt < 4; ++nt) {
      s16x8 kb0 = *(const s16x8*)&Ks[(nt * 16 + r15) * LDK + quad * 8];
      s16x8 kb1 = *(const s16x8*)&Ks[(nt * 16 + r15) * LDK + 32 + quad * 8];
      f32x4v z = {0.f, 0.f, 0.f, 0.f};
      z = __builtin_amdgcn_mfma_f32_16x16x32_bf16(qa[0], kb0, z, 0, 0, 0);
      z = __builtin_amdgcn_mfma_f32_16x16x32_bf16(qa[1], kb1, z, 0, 0, 0);
      sa[nt] = z;
    }
    const bool diag = (key0 == q0);  // only the diagonal tile needs masking

    // ---- online softmax; C-layout row = quad*4+r, col = nt*16+r15 ----
#pragma unroll
    for (int r = 0; r < 4; ++r) {
      int q = q0 + w * 16 + quad * 4 + r;
      float sv[4];
#pragma unroll
      for (int nt = 0; nt < 4; ++nt) {
        sv[nt] = sa[nt][r] * SCALE;
        if (diag && (key0 + nt * 16 + r15 > q)) sv[nt] = -1e30f;
      }
      float mx = fmaxf(fmaxf(sv[0], sv[1]), fmaxf(sv[2], sv[3]));
      mx = fmaxf(mx, __shfl_xor(mx, 8));
      mx = fmaxf(mx, __shfl_xor(mx, 4));
      mx = fmaxf(mx, __shfl_xor(mx, 2));
      mx = fmaxf(mx, __shfl_xor(mx, 1));
      float mnew = fmaxf(mm[r], mx);
      float alpha = __expf(mm[r] - mnew);
      float ps = 0.f;
#pragma unroll
      for (int nt = 0; nt < 4; ++nt) {
        float p = __expf(sv[nt] - mnew);
        ps += p;
        Ps[w][(quad * 4 + r) * LDK + nt * 16 + r15] =
            (unsigned short)bfrne(p);
      }
      ps += __shfl_xor(ps, 8);
      ps += __shfl_xor(ps, 4);
      ps += __shfl_xor(ps, 2);
      ps += __shfl_xor(ps, 1);
      ll[r] = ll[r] * alpha + ps;
      mm[r] = mnew;
#pragma unroll
      for (int dt = 0; dt < 4; ++dt) oacc[dt][r] *= alpha;
    }
    // per-wave LDS round-trip: drain this wave's Ps writes before reading
    asm volatile("s_waitcnt lgkmcnt(0)" ::: "memory");
    __builtin_amdgcn_sched_barrier(0);

    // ---- O += P @ V ----
    s16x8 pa0 = *(const s16x8*)&Ps[w][r15 * LDK + quad * 8];
    s16x8 pa1 = *(const s16x8*)&Ps[w][r15 * LDK + 32 + quad * 8];
#pragma unroll
    for (int dt = 0; dt < 4; ++dt) {
      s16x8 vb0 = *(const s16x8*)&Vt[(dt * 16 + r15) * LDK + quad * 8];
      s16x8 vb1 = *(const s16x8*)&Vt[(dt * 16 + r15) * LDK + 32 + quad * 8];
      oacc[dt] =
          __builtin_amdgcn_mfma_f32_16x16x32_bf16(pa0, vb0, oacc[dt], 0, 0, 0);
      oacc[dt] =
          __builtin_amdgcn_mfma_f32_16x16x32_bf16(pa1, vb1, oacc[dt], 0, 0, 0);
    }
  }

  // ---- write out bf16 (row = quad*4+r, col = dt*16+r15) ----
#pragma unroll
  for (int r = 0; r < 4; ++r) {
    int q = q0 + w * 16 + quad * 4 + r;
    if (q < T) {
      float inv = 1.f / ll[r];
      unsigned short* yp = Yb + ((size_t)b * T + q) * C + hbase;
#pragma unroll
      for (int dt = 0; dt < 4; ++dt)
        yp[dt * 16 + r15] = (unsigned short)bfrne(oacc[dt][r] * inv);
    }
  }
}

extern "C" void kernel_launch(void* const* d_in, const int* in_sizes, int n_in,
                              void* d_out, int out_size, void* d_ws,
                              size_t ws_size, hipStream_t stream) {
  const float* x     = (const float*)d_in[0];
  const float* dw_w  = (const float*)d_in[1];
  const float* dw_b  = (const float*)d_in[2];
  const float* pw_w  = (const float*)d_in[3];
  const float* pw_b  = (const float*)d_in[4];
  const float* cln_g = (const float*)d_in[5];
  const float* cln_b = (const float*)d_in[6];
  const float* wq    = (const float*)d_in[7];
  const float* bq    = (const float*)d_in[8];
  const float* wk    = (const float*)d_in[9];
  const float* bk    = (const float*)d_in[10];
  const float* wv    = (const float*)d_in[11];
  const float* bv    = (const float*)d_in[12];
  const float* wo    = (const float*)d_in[13];
  const float* bo    = (const float*)d_in[14];
  const float* aln_g = (const float*)d_in[15];
  const float* aln_b = (const float*)d_in[16];
  const float* w1    = (const float*)d_in[17];
  const float* b1    = (const float*)d_in[18];
  const float* w2    = (const float*)d_in[19];
  const float* b2    = (const float*)d_in[20];
  const float* fln_g = (const float*)d_in[21];
  const float* fln_b = (const float*)d_in[22];

  float* ws = (float*)d_ws;
  float* A  = ws;                      // bias concat + ffn1-out (bf16 spans A,Bf)
  float* Bf = ws + (size_t)BTC;        // bf16 activation slot
  float* R0 = ws + (size_t)2 * BTC;    // QKV bf16 (spans into R1) / f32 outs
  float* R1 = ws + (size_t)3 * BTC;    // O-proj f32 out
  float* R2 = ws + (size_t)4 * BTC;    // ffn1 input bf16
  unsigned short* WA = (unsigned short*)(ws + (size_t)5 * BTC);  // 7.4 MB
  float* out = (float*)d_out;          // 3 layer outputs, f32

  unsigned short* xbf   = (unsigned short*)Bf;   // conv-GEMM in / QKV in / attn out
  unsigned short* qkvbf = (unsigned short*)R0;   // QKV GEMM out [M,1536] bf16
  unsigned short* fbf   = (unsigned short*)R2;   // ffn1 input bf16
  unsigned short* hbf   = (unsigned short*)A;    // ffn1 output bf16 (spans A,Bf)
  float* qkvb = A;                               // 1536-wide concat bias

  dim3 blk(256);
  dim3 gemmC(C / 128, 63);        // N=512
  dim3 gemmQKV(3 * C / 128, 63);  // N=1536
  dim3 gemmH(HID / 128, 63);      // N=2048
  dim3 convG(T * C / 512, B);     // 2 channels/thread
  dim3 attnG((T + 63) / 64, NH, B);
  int cvtwB = SEG_END / 2048;     // 1792 blocks

  for (int l = 0; l < 3; ++l) {
    float* h = out + (size_t)l * BTC;
    const float* hin = (l == 0) ? x : out + (size_t)(l - 1) * BTC;
    cvtw_kernel<<<cvtwB, blk, 0, stream>>>(
        pw_w + (size_t)(2 * l) * CC, pw_w + (size_t)(2 * l + 1) * CC,
        wq + (size_t)l * CC, wk + (size_t)l * CC, wv + (size_t)l * CC,
        wo + (size_t)l * CC, w1 + (size_t)l * HID * C,
        w2 + (size_t)l * C * HID, WA);
    biascat_kernel<<<6, blk, 0, stream>>>(bq + (size_t)l * C,
                                          bk + (size_t)l * C,
                                          bv + (size_t)l * C, qkvb);
    // ---- 2 conv blocks ----
    for (int cb = 0; cb < 2; ++cb) {
      int lc = l * 2 + cb;
      const float* src = (cb == 0) ? hin : h;
      dwconv_kernel<<<convG, blk, 0, stream>>>(src, dw_w + (size_t)lc * C * KW,
                                               dw_b + (size_t)lc * C, xbf);
      gemm_mfma<true, false, false><<<gemmC, blk, 0, stream>>>(
          xbf, WA + (cb ? SEG_PW1 : SEG_PW0), pw_b + (size_t)lc * C, R0, C, C);
      if (cb == 0)
        ln_kernel<false><<<M / 4, blk, 0, stream>>>(
            R0, cln_g + (size_t)lc * C, cln_b + (size_t)lc * C, h, nullptr);
      else  // dual: bf16 copy feeds fused QKV GEMM
        ln_kernel<true><<<M / 4, blk, 0, stream>>>(
            R0, cln_g + (size_t)lc * C, cln_b + (size_t)lc * C, h, xbf);
    }
    // ---- attention ----
    gemm_mfma<true, false, true><<<gemmQKV, blk, 0, stream>>>(
        xbf, WA + SEG_WQ, qkvb, qkvbf, 3 * C, C);
    attn_mfma_kernel<<<attnG, blk, 0, stream>>>(qkvbf, xbf);
    gemm_mfma<true, false, false><<<gemmC, blk, 0, stream>>>(
        xbf, WA + SEG_WO, bo + (size_t)l * C, R1, C, C);
    ln_kernel<true><<<M / 4, blk, 0, stream>>>(
        R1, aln_g + (size_t)l * C, aln_b + (size_t)l * C, h, fbf);
    // ---- FFN ----
    gemm_mfma<true, true, true><<<gemmH, blk, 0, stream>>>(
        fbf, WA + SEG_W1, b1 + (size_t)l * HID, hbf, HID, C);
    gemm_mfma<true, false, false><<<gemmC, blk, 0, stream>>>(
        hbf, WA + SEG_W2, b2 + (size_t)l * C, R0, C, HID);
    ln_kernel<false><<<M / 4, blk, 0, stream>>>(
        R0, fln_g + (size_t)l * C, fln_b + (size_t)l * C, h, nullptr);
  }
}